// Round 1
// baseline (646.695 us; speedup 1.0000x reference)
//
#include <hip/hip_runtime.h>
#include <math.h>

#define N_ROWS   65536
#define K_EMB    1024
#define D_EMB    256
#define BM       128
#define BN       128
#define BK       64

// ---------------- Phase A: fused distance-GEMM + per-row argmin ----------------
// 256 threads = 16(tx: cols) x 16(ty: rows), 8x8 register tile.
// LDS tiles stored transposed [d][r] with XOR swizzle so staging writes are
// conflict-free at stride 128 (total 64 KB static -> 2 blocks/CU).
__global__ __launch_bounds__(256, 2)
void argmin_kernel(const float* __restrict__ x,
                   const float* __restrict__ ew,
                   const float* __restrict__ esq,
                   int* __restrict__ indices)
{
    __shared__ float xs[BK * BM];
    __shared__ float es[BK * BN];

    const int t  = threadIdx.x;
    const int tx = t & 15;
    const int ty = t >> 4;
    const int r0 = blockIdx.x * BM;

    float mv[8];
    int   mi[8];
#pragma unroll
    for (int i = 0; i < 8; ++i) { mv[i] = 3.4e38f; mi[i] = 0; }

    for (int kc = 0; kc < K_EMB / BN; ++kc) {
        float s[8][8];
#pragma unroll
        for (int i = 0; i < 8; ++i)
#pragma unroll
            for (int j = 0; j < 8; ++j) s[i][j] = 0.0f;

        for (int dc = 0; dc < D_EMB / BK; ++dc) {
            // stage BKx128 x-tile and e-tile, transposed + swizzled
#pragma unroll
            for (int it = 0; it < 8; ++it) {
                int q  = it * 256 + t;
                int r  = q >> 4;      // row/col within tile [0,128)
                int d4 = q & 15;      // float4 index along d [0,16)
                float4 xv = *(const float4*)(x  + (size_t)(r0 + r) * D_EMB + dc * BK + d4 * 4);
                float4 ev = *(const float4*)(ew + (size_t)(kc * BN + r) * D_EMB + dc * BK + d4 * 4);
                int rs = r ^ ((d4 & 7) << 2);
                xs[(d4 * 4 + 0) * BM + rs] = xv.x;
                xs[(d4 * 4 + 1) * BM + rs] = xv.y;
                xs[(d4 * 4 + 2) * BM + rs] = xv.z;
                xs[(d4 * 4 + 3) * BM + rs] = xv.w;
                es[(d4 * 4 + 0) * BN + rs] = ev.x;
                es[(d4 * 4 + 1) * BN + rs] = ev.y;
                es[(d4 * 4 + 2) * BN + rs] = ev.z;
                es[(d4 * 4 + 3) * BN + rs] = ev.w;
            }
            __syncthreads();

#pragma unroll 4
            for (int d = 0; d < BK; ++d) {
                int sw = ((d >> 2) & 7) << 2;
                int ao = d * BM + ((ty * 8) ^ sw);
                int bo = d * BN + ((tx * 8) ^ sw);
                float4 a0 = *(const float4*)&xs[ao];
                float4 a1 = *(const float4*)&xs[ao ^ 4];
                float4 b0 = *(const float4*)&es[bo];
                float4 b1 = *(const float4*)&es[bo ^ 4];
                float a[8] = {a0.x, a0.y, a0.z, a0.w, a1.x, a1.y, a1.z, a1.w};
                float b[8] = {b0.x, b0.y, b0.z, b0.w, b1.x, b1.y, b1.z, b1.w};
#pragma unroll
                for (int i = 0; i < 8; ++i)
#pragma unroll
                    for (int j = 0; j < 8; ++j)
                        s[i][j] += a[i] * b[j];
            }
            __syncthreads();
        }

        // fold this k-chunk into the running argmin (k ascends, strict < keeps first)
#pragma unroll
        for (int j = 0; j < 8; ++j) {
            int k = kc * BN + tx * 8 + j;
            float ek = esq[k];
#pragma unroll
            for (int i = 0; i < 8; ++i) {
                float sc = ek - 2.0f * s[i][j];
                if (sc < mv[i]) { mv[i] = sc; mi[i] = k; }
            }
        }
    }

    // reduce across the 16 tx lanes that share each row (ties -> smaller index)
#pragma unroll
    for (int off = 1; off < 16; off <<= 1) {
#pragma unroll
        for (int i = 0; i < 8; ++i) {
            float ov = __shfl_xor(mv[i], off);
            int   oi = __shfl_xor(mi[i], off);
            if (ov < mv[i] || (ov == mv[i] && oi < mi[i])) { mv[i] = ov; mi[i] = oi; }
        }
    }
    if (tx == 0) {
#pragma unroll
        for (int i = 0; i < 8; ++i)
            indices[r0 + ty * 8 + i] = mi[i];
    }
}

// ---------------- codebook row squared norms ----------------
__global__ void esq_kernel(const float* __restrict__ ew, float* __restrict__ esq)
{
    const int k = blockIdx.x;
    const int lane = threadIdx.x;  // 64 threads
    float4 v = *(const float4*)(ew + (size_t)k * D_EMB + lane * 4);
    float s = v.x * v.x + v.y * v.y + v.z * v.z + v.w * v.w;
#pragma unroll
    for (int off = 32; off > 0; off >>= 1) s += __shfl_down(s, off);
    if (lane == 0) esq[k] = s;
}

// ---------------- Phase B: quantize + loss partials + scatter stats ----------------
__global__ __launch_bounds__(256)
void quant_kernel(const float* __restrict__ x,
                  const float* __restrict__ ew,
                  const int* __restrict__ indices,
                  float* __restrict__ out_q,
                  float* __restrict__ dw,
                  int* __restrict__ counts,
                  double* __restrict__ loss_buckets)
{
    const int row = blockIdx.x;
    const int d   = threadIdx.x;
    const int idx = indices[row];  // wave-uniform
    const float xv = x[(size_t)row * D_EMB + d];
    const float qv = ew[(size_t)idx * D_EMB + d];
    out_q[(size_t)row * D_EMB + d] = xv + (qv - xv);  // straight-through == quantized
    const float diff = qv - xv;
    float s = diff * diff;
#pragma unroll
    for (int off = 32; off > 0; off >>= 1) s += __shfl_down(s, off);
    __shared__ float part[4];
    const int lane = d & 63, wv = d >> 6;
    if (lane == 0) part[wv] = s;
    __syncthreads();
    atomicAdd(&dw[(size_t)idx * D_EMB + d], xv);
    if (d == 0) {
        float tot = part[0] + part[1] + part[2] + part[3];
        atomicAdd(&loss_buckets[row & 255], (double)tot);
        atomicAdd(&counts[idx], 1);
    }
}

// ---------------- C1: scalars + cluster sizes (one block of 1024) ----------------
__global__ __launch_bounds__(1024)
void finalize_small(const float* __restrict__ ema_cs,
                    const int* __restrict__ counts,
                    const double* __restrict__ loss_buckets,
                    float* __restrict__ cs_ws,
                    float* __restrict__ out_loss,
                    float* __restrict__ out_perp,
                    float* __restrict__ out_ncs)
{
    __shared__ float  red[1024];
    __shared__ double redd[256];
    const int k = threadIdx.x;
    const float cnt = (float)counts[k];
    const float ncs = 0.99f * ema_cs[k] + 0.01f * cnt;
    out_ncs[k] = ncs;
    red[k] = ncs;
    __syncthreads();
    for (int off = 512; off > 0; off >>= 1) {
        if (k < off) red[k] += red[k + off];
        __syncthreads();
    }
    const float n = red[0];
    __syncthreads();
    cs_ws[k] = (ncs + 1e-5f) / (n + 1024.0f * 1e-5f) * n;

    // perplexity (counts sum to N exactly)
    const float p = cnt / 65536.0f;
    red[k] = p * logf(p + 1e-10f);
    if (k < 256) redd[k] = loss_buckets[k];
    __syncthreads();
    for (int off = 512; off > 0; off >>= 1) {
        if (k < off) red[k] += red[k + off];
        __syncthreads();
    }
    if (k == 0) out_perp[0] = expf(-red[0]);
    for (int off = 128; off > 0; off >>= 1) {
        if (k < off) redd[k] += redd[k + off];
        __syncthreads();
    }
    if (k == 0) out_loss[0] = (float)(0.25 * (redd[0] / 16777216.0));
}

// ---------------- C2: codebook update ----------------
__global__ __launch_bounds__(256)
void codebook_kernel(const float* __restrict__ ema_w,
                     const float* __restrict__ dw,
                     const float* __restrict__ cs_ws,
                     float* __restrict__ out_emb,
                     float* __restrict__ out_ema)
{
    const int k = blockIdx.x;
    const int d = threadIdx.x;
    const size_t o = (size_t)k * D_EMB + d;
    const float nev = 0.99f * ema_w[o] + 0.01f * dw[o];
    out_ema[o] = nev;
    out_emb[o] = nev / cs_ws[k];
}

extern "C" void kernel_launch(void* const* d_in, const int* in_sizes, int n_in,
                              void* d_out, int out_size, void* d_ws, size_t ws_size,
                              hipStream_t stream)
{
    const float* x       = (const float*)d_in[0];  // 32*2048*256
    const float* ew      = (const float*)d_in[1];  // 1024*256
    const float* ema_cs  = (const float*)d_in[2];  // 1024
    const float* ema_w   = (const float*)d_in[3];  // 1024*256

    float* out       = (float*)d_out;
    float* out_loss  = out;                         // [1]
    float* out_q     = out + 1;                     // [16777216]
    float* out_perp  = out + 1 + 16777216;          // [1]
    float* out_emb   = out_perp + 1;                // [262144]
    float* out_ncs   = out_emb + 262144;            // [1024]
    float* out_ema   = out_ncs + 1024;              // [262144]

    char* ws = (char*)d_ws;
    float*  dw           = (float*)(ws);             // 1,048,576 B
    int*    counts       = (int*)(ws + 1048576);     // 4,096 B
    double* loss_buckets = (double*)(ws + 1052672);  // 2,048 B
    float*  esq          = (float*)(ws + 1054720);   // 4,096 B
    float*  cs_ws        = (float*)(ws + 1058816);   // 4,096 B
    int*    indices      = (int*)(ws + 1062912);     // 262,144 B

    // zero the accumulators (dw + counts + loss buckets)
    hipMemsetAsync(ws, 0, 1054720, stream);

    esq_kernel<<<K_EMB, 64, 0, stream>>>(ew, esq);
    argmin_kernel<<<N_ROWS / BM, 256, 0, stream>>>(x, ew, esq, indices);
    quant_kernel<<<N_ROWS, 256, 0, stream>>>(x, ew, indices, out_q, dw, counts, loss_buckets);
    finalize_small<<<1, 1024, 0, stream>>>(ema_cs, counts, loss_buckets, cs_ws,
                                           out_loss, out_perp, out_ncs);
    codebook_kernel<<<K_EMB, 256, 0, stream>>>(ema_w, dw, cs_ws, out_emb, out_ema);
}

// Round 2
// 461.975 us; speedup vs baseline: 1.3998x; 1.3998x over previous
//
#include <hip/hip_runtime.h>
#include <math.h>

#define N_ROWS   65536
#define K_EMB    1024
#define D_EMB    256

typedef __attribute__((ext_vector_type(8)))  short short8;
typedef __attribute__((ext_vector_type(4)))  short short4v;
typedef __attribute__((ext_vector_type(16))) float floatx16;

__device__ inline unsigned short f2bf(float f) {
    unsigned u = __float_as_uint(f);
    unsigned r = u + 0x7fffu + ((u >> 16) & 1u);
    return (unsigned short)(r >> 16);
}
__device__ inline float bf2f(unsigned short s) {
    return __uint_as_float(((unsigned)s) << 16);
}

// ---------------- prep: 0.5*||e||^2 + negated bf16 hi/lo codebook ----------------
__global__ __launch_bounds__(64)
void prep_e(const float* __restrict__ ew, float* __restrict__ half_esq,
            short* __restrict__ neg_hi, short* __restrict__ neg_lo)
{
    const int k = blockIdx.x;
    const int d = threadIdx.x;  // 64 threads, 4 elems each
    float4 v = *(const float4*)(ew + (size_t)k * D_EMB + d * 4);
    float s = v.x * v.x + v.y * v.y + v.z * v.z + v.w * v.w;
#pragma unroll
    for (int off = 32; off > 0; off >>= 1) s += __shfl_down(s, off);
    if (d == 0) half_esq[k] = 0.5f * s;

    float f[4] = {-v.x, -v.y, -v.z, -v.w};
    short4v h, l;
#pragma unroll
    for (int j = 0; j < 4; ++j) {
        unsigned short hh = f2bf(f[j]);
        h[j] = (short)hh;
        l[j] = (short)f2bf(f[j] - bf2f(hh));
    }
    *(short4v*)(neg_hi + (size_t)k * D_EMB + d * 4) = h;
    *(short4v*)(neg_lo + (size_t)k * D_EMB + d * 4) = l;
}

// ---------------- Phase A: MFMA argmin (bf16 hi/lo split, 3-pass) ----------------
// Block: 64 rows staged once into LDS as bf16 hi/lo (XOR-swizzled 16B chunks).
// 4 waves = 2 row-halves x 2 code-halves. e is the A operand (negated), x is B.
// acc = 0.5*esq[code] - x.e  ==> per-row argmin over acc directly.
__global__ __launch_bounds__(256, 2)
void argmin_mfma(const float* __restrict__ x,
                 const short* __restrict__ neg_hi,
                 const short* __restrict__ neg_lo,
                 const float* __restrict__ half_esq,
                 int* __restrict__ indices)
{
    __shared__ short xs_hi[64 * 256];
    __shared__ short xs_lo[64 * 256];

    const int t  = threadIdx.x;
    const int r0 = blockIdx.x * 64;

    // ---- stage x: fp32 -> bf16 hi/lo, swizzled so frag reads are 4-way optimal ----
#pragma unroll
    for (int i = 0; i < 8; ++i) {
        int q   = i * 256 + t;
        int row = q >> 5;        // [0,64)
        int g8  = q & 31;        // 8-float group within row
        const float* gp = x + (size_t)(r0 + row) * D_EMB + g8 * 8;
        float4 a = *(const float4*)gp;
        float4 b = *(const float4*)(gp + 4);
        float f[8] = {a.x, a.y, a.z, a.w, b.x, b.y, b.z, b.w};
        short8 h8, l8;
#pragma unroll
        for (int j = 0; j < 8; ++j) {
            unsigned short hh = f2bf(f[j]);
            h8[j] = (short)hh;
            l8[j] = (short)f2bf(f[j] - bf2f(hh));
        }
        int off = row * 256 + ((g8 ^ (row & 7)) << 3);
        *(short8*)(xs_hi + off) = h8;
        *(short8*)(xs_lo + off) = l8;
    }
    __syncthreads();

    const int w      = t >> 6;
    const int lane   = t & 63;
    const int rbase  = (w & 1) * 32;     // row half
    const int cb     = (w >> 1) * 512;   // code half
    const int l31    = lane & 31;
    const int half   = lane >> 5;
    const int key    = l31 & 7;          // swizzle key ((rbase+l31)&7 == l31&7)
    const int ldsrow = rbase + l31;
    const short* bbase_h = xs_hi + ldsrow * 256;
    const short* bbase_l = xs_lo + ldsrow * 256;

    float mv = 3.4e38f;
    int   mi = 0;

    for (int cp = 0; cp < 8; ++cp) {
        const int c0 = cb + cp * 64;
        const int c1 = c0 + 32;

        floatx16 acc0, acc1;
#pragma unroll
        for (int rq = 0; rq < 4; ++rq) {
            float4 e0 = *(const float4*)(half_esq + c0 + rq * 8 + half * 4);
            float4 e1 = *(const float4*)(half_esq + c1 + rq * 8 + half * 4);
            acc0[rq * 4 + 0] = e0.x; acc0[rq * 4 + 1] = e0.y;
            acc0[rq * 4 + 2] = e0.z; acc0[rq * 4 + 3] = e0.w;
            acc1[rq * 4 + 0] = e1.x; acc1[rq * 4 + 1] = e1.y;
            acc1[rq * 4 + 2] = e1.z; acc1[rq * 4 + 3] = e1.w;
        }

        const short* a0base_h = neg_hi + (size_t)(c0 + l31) * D_EMB + half * 8;
        const short* a0base_l = neg_lo + (size_t)(c0 + l31) * D_EMB + half * 8;
        const short* a1base_h = neg_hi + (size_t)(c1 + l31) * D_EMB + half * 8;
        const short* a1base_l = neg_lo + (size_t)(c1 + l31) * D_EMB + half * 8;

#pragma unroll 4
        for (int kt = 0; kt < 16; ++kt) {
            int coff = (((2 * kt + half) ^ key) << 3);
            short8 bh = *(const short8*)(bbase_h + coff);
            short8 bl = *(const short8*)(bbase_l + coff);
            short8 a0h = *(const short8*)(a0base_h + kt * 16);
            short8 a0l = *(const short8*)(a0base_l + kt * 16);
            short8 a1h = *(const short8*)(a1base_h + kt * 16);
            short8 a1l = *(const short8*)(a1base_l + kt * 16);
            acc0 = __builtin_amdgcn_mfma_f32_32x32x16_bf16(a0h, bh, acc0, 0, 0, 0);
            acc1 = __builtin_amdgcn_mfma_f32_32x32x16_bf16(a1h, bh, acc1, 0, 0, 0);
            acc0 = __builtin_amdgcn_mfma_f32_32x32x16_bf16(a0h, bl, acc0, 0, 0, 0);
            acc1 = __builtin_amdgcn_mfma_f32_32x32x16_bf16(a1h, bl, acc1, 0, 0, 0);
            acc0 = __builtin_amdgcn_mfma_f32_32x32x16_bf16(a0l, bh, acc0, 0, 0, 0);
            acc1 = __builtin_amdgcn_mfma_f32_32x32x16_bf16(a1l, bh, acc1, 0, 0, 0);
        }

        // fold: C row = code-in-chunk = (r&3) + 8*(r>>2) + 4*half; col = x-row = l31
#pragma unroll
        for (int r = 0; r < 16; ++r) {
            int code0 = c0 + (r & 3) + ((r >> 2) << 3) + half * 4;
            float v0 = acc0[r];
            if (v0 < mv || (v0 == mv && code0 < mi)) { mv = v0; mi = code0; }
            int code1 = code0 + 32;
            float v1 = acc1[r];
            if (v1 < mv || (v1 == mv && code1 < mi)) { mv = v1; mi = code1; }
        }
    }

    // combine the two 32-lane halves (disjoint code subsets, same x-row)
    {
        float ov = __shfl_xor(mv, 32);
        int   oi = __shfl_xor(mi, 32);
        if (ov < mv || (ov == mv && oi < mi)) { mv = ov; mi = oi; }
    }

    // cross-wave (code-half) combine via LDS (xs reuse is safe after this barrier)
    __syncthreads();
    float* cmv = (float*)xs_hi;
    int*   cmi = (int*)xs_lo;
    if (half == 0) {
        int slot = (w >> 1) * 64 + rbase + l31;
        cmv[slot] = mv;
        cmi[slot] = mi;
    }
    __syncthreads();
    if (t < 64) {
        float v0 = cmv[t];      int i0 = cmi[t];
        float v1 = cmv[64 + t]; int i1 = cmi[64 + t];
        indices[r0 + t] = (v1 < v0 || (v1 == v0 && i1 < i0)) ? i1 : i0;
    }
}

// ---------------- Phase B: quantize + loss partials + scatter stats ----------------
__global__ __launch_bounds__(256)
void quant_kernel(const float* __restrict__ x,
                  const float* __restrict__ ew,
                  const int* __restrict__ indices,
                  float* __restrict__ out_q,
                  float* __restrict__ dw,
                  int* __restrict__ counts,
                  double* __restrict__ loss_buckets)
{
    const int row = blockIdx.x;
    const int d   = threadIdx.x;
    const int idx = indices[row];  // wave-uniform
    const float xv = x[(size_t)row * D_EMB + d];
    const float qv = ew[(size_t)idx * D_EMB + d];
    out_q[(size_t)row * D_EMB + d] = xv + (qv - xv);  // straight-through == quantized
    const float diff = qv - xv;
    float s = diff * diff;
#pragma unroll
    for (int off = 32; off > 0; off >>= 1) s += __shfl_down(s, off);
    __shared__ float part[4];
    const int lane = d & 63, wv = d >> 6;
    if (lane == 0) part[wv] = s;
    __syncthreads();
    atomicAdd(&dw[(size_t)idx * D_EMB + d], xv);
    if (d == 0) {
        float tot = part[0] + part[1] + part[2] + part[3];
        atomicAdd(&loss_buckets[row & 255], (double)tot);
        atomicAdd(&counts[idx], 1);
    }
}

// ---------------- C1: scalars + cluster sizes (one block of 1024) ----------------
__global__ __launch_bounds__(1024)
void finalize_small(const float* __restrict__ ema_cs,
                    const int* __restrict__ counts,
                    const double* __restrict__ loss_buckets,
                    float* __restrict__ cs_ws,
                    float* __restrict__ out_loss,
                    float* __restrict__ out_perp,
                    float* __restrict__ out_ncs)
{
    __shared__ float  red[1024];
    __shared__ double redd[256];
    const int k = threadIdx.x;
    const float cnt = (float)counts[k];
    const float ncs = 0.99f * ema_cs[k] + 0.01f * cnt;
    out_ncs[k] = ncs;
    red[k] = ncs;
    __syncthreads();
    for (int off = 512; off > 0; off >>= 1) {
        if (k < off) red[k] += red[k + off];
        __syncthreads();
    }
    const float n = red[0];
    __syncthreads();
    cs_ws[k] = (ncs + 1e-5f) / (n + 1024.0f * 1e-5f) * n;

    const float p = cnt / 65536.0f;
    red[k] = p * logf(p + 1e-10f);
    if (k < 256) redd[k] = loss_buckets[k];
    __syncthreads();
    for (int off = 512; off > 0; off >>= 1) {
        if (k < off) red[k] += red[k + off];
        __syncthreads();
    }
    if (k == 0) out_perp[0] = expf(-red[0]);
    for (int off = 128; off > 0; off >>= 1) {
        if (k < off) redd[k] += redd[k + off];
        __syncthreads();
    }
    if (k == 0) out_loss[0] = (float)(0.25 * (redd[0] / 16777216.0));
}

// ---------------- C2: codebook update ----------------
__global__ __launch_bounds__(256)
void codebook_kernel(const float* __restrict__ ema_w,
                     const float* __restrict__ dw,
                     const float* __restrict__ cs_ws,
                     float* __restrict__ out_emb,
                     float* __restrict__ out_ema)
{
    const int k = blockIdx.x;
    const int d = threadIdx.x;
    const size_t o = (size_t)k * D_EMB + d;
    const float nev = 0.99f * ema_w[o] + 0.01f * dw[o];
    out_ema[o] = nev;
    out_emb[o] = nev / cs_ws[k];
}

extern "C" void kernel_launch(void* const* d_in, const int* in_sizes, int n_in,
                              void* d_out, int out_size, void* d_ws, size_t ws_size,
                              hipStream_t stream)
{
    const float* x       = (const float*)d_in[0];  // 32*2048*256
    const float* ew      = (const float*)d_in[1];  // 1024*256
    const float* ema_cs  = (const float*)d_in[2];  // 1024
    const float* ema_w   = (const float*)d_in[3];  // 1024*256

    float* out       = (float*)d_out;
    float* out_loss  = out;                         // [1]
    float* out_q     = out + 1;                     // [16777216]
    float* out_perp  = out + 1 + 16777216;          // [1]
    float* out_emb   = out_perp + 1;                // [262144]
    float* out_ncs   = out_emb + 262144;            // [1024]
    float* out_ema   = out_ncs + 1024;              // [262144]

    char* ws = (char*)d_ws;
    float*  dw           = (float*)(ws);             // 1,048,576 B
    int*    counts       = (int*)(ws + 1048576);     // 4,096 B
    double* loss_buckets = (double*)(ws + 1052672);  // 2,048 B
    float*  half_esq     = (float*)(ws + 1054720);   // 4,096 B
    float*  cs_ws        = (float*)(ws + 1058816);   // 4,096 B
    int*    indices      = (int*)(ws + 1062912);     // 262,144 B

    // scratch bf16 codebook tables live inside out_q (overwritten later by
    // quant_kernel). out+4 is 16B-aligned; 1 MB total, well inside 64 MB.
    short* neg_hi = (short*)(out + 4);               // 1024*256 shorts
    short* neg_lo = (short*)(out + 4 + 131072);      // 1024*256 shorts

    // zero the accumulators (dw + counts + loss buckets)
    hipMemsetAsync(ws, 0, 1054720, stream);

    prep_e<<<K_EMB, 64, 0, stream>>>(ew, half_esq, neg_hi, neg_lo);
    argmin_mfma<<<N_ROWS / 64, 256, 0, stream>>>(x, neg_hi, neg_lo, half_esq, indices);
    quant_kernel<<<N_ROWS, 256, 0, stream>>>(x, ew, indices, out_q, dw, counts, loss_buckets);
    finalize_small<<<1, 1024, 0, stream>>>(ema_cs, counts, loss_buckets, cs_ws,
                                           out_loss, out_perp, out_ncs);
    codebook_kernel<<<K_EMB, 256, 0, stream>>>(ema_w, dw, cs_ws, out_emb, out_ema);
}